// Round 16
// baseline (1401.969 us; speedup 1.0000x reference)
//
#include <hip/hip_runtime.h>
#include <math.h>

#define S_LEN 2048
#define DMODEL 2048
#define NHQ 16
#define NHK 4
#define HDIM 128
#define PDIM 8192
#define VOCAB 32000
#define NQKV 3072          // D + 2*HK*HD
#define EPSI 1e-5f

typedef unsigned short u16;
typedef unsigned int u32;
typedef __bf16 bf16x8 __attribute__((ext_vector_type(8)));
typedef float f32x4 __attribute__((ext_vector_type(4)));

__device__ __forceinline__ u16 f2bf(float f){
  u32 u = __builtin_bit_cast(u32, f);
  u += 0x7fffu + ((u >> 16) & 1u);   // RNE
  return (u16)(u >> 16);
}
__device__ __forceinline__ float bf2f(u16 h){
  u32 u = ((u32)h) << 16;
  return __builtin_bit_cast(float, u);
}
__device__ __forceinline__ bf16x8 ld8(const u16* p){
  return __builtin_bit_cast(bf16x8, *(const uint4*)p);
}
__device__ __forceinline__ f32x4 mfma16(bf16x8 a, bf16x8 b, f32x4 c){
  return __builtin_amdgcn_mfma_f32_16x16x32_bf16(a, b, c, 0, 0, 0);
}

#define GLOAD_LDS16(gp, lp) __builtin_amdgcn_global_load_lds( \
    (__attribute__((address_space(1))) void*)(gp), \
    (__attribute__((address_space(3))) void*)(lp), 16, 0, 0)

// Swizzled LDS tile layout: [Rows][32k] bf16 stored as row-PAIRS; line Rp=R>>1
// holds rows {2Rp,2Rp+1} x 32 k = 128 B = 8 slots of 16 B, slot XOR (Rp&7).
// gload_lds dest LINEAR; permutation applied to per-lane GLOBAL source.
// 0 bank conflicts measured (R3-R15).
__device__ __forceinline__ bf16x8 lds_frag(const u16* Lb, int R, int g){
  const int Rp = R >> 1;
  const int s8 = (((R & 1) << 2) | g) ^ (Rp & 7);
  return ld8(Lb + Rp * 64 + s8 * 8);
}
__device__ __forceinline__ void stage_sw(const u16* base, long row0, int kstride, int kt,
                                         int q, u16* Ldst_waveuniform){
  const int Rp = q >> 3;
  const int u = (q & 7) ^ (Rp & 7);
  const int R = (Rp << 1) | (u >> 2);
  const u16* gp = base + (row0 + R) * (long)kstride + kt + ((u & 3) << 3);
  GLOAD_LDS16(gp, Ldst_waveuniform);
}

// XCD-contiguous, bm-grouped block mapping.
__device__ __forceinline__ void map_bmn(int id0, int nwg, int nbn, int G,
                                        int& bm, int& bn){
  const int cpx = nwg >> 3;               // nwg % 8 == 0 at all call sites
  const int id = (id0 & 7) * cpx + (id0 >> 3);
  const int bmi = id % G;
  const int r2 = id / G;
  bn = r2 % nbn;
  bm = (r2 / nbn) * G + bmi;
}

// -------------------- embed gather --------------------
__global__ void k_embed(const int* __restrict__ tok, const float* __restrict__ emb,
                        float* __restrict__ x){
  const int s = blockIdx.x, t = threadIdx.x;
  const long r = tok[s];
  const float4* src = (const float4*)(emb + r * DMODEL);
  float4* dst = (float4*)(x + (long)s * DMODEL);
  dst[t] = src[t];
  dst[t + 256] = src[t + 256];
}

// -------------------- RMSNorm: fp32 in -> bf16 out --------------------
__global__ void k_rmsnorm(const float* __restrict__ x, const float* __restrict__ w,
                          u16* __restrict__ out){
  const int s = blockIdx.x, t = threadIdx.x;
  const float4* xr = (const float4*)(x + (long)s * DMODEL);
  const float4 a = xr[t], b = xr[t + 256];
  float ss = a.x*a.x + a.y*a.y + a.z*a.z + a.w*a.w
           + b.x*b.x + b.y*b.y + b.z*b.z + b.w*b.w;
  #pragma unroll
  for (int off = 32; off > 0; off >>= 1) ss += __shfl_down(ss, off, 64);
  __shared__ float part[4];
  if ((t & 63) == 0) part[t >> 6] = ss;
  __syncthreads();
  const float r = rsqrtf((part[0] + part[1] + part[2] + part[3]) * (1.f / 2048.f) + EPSI);
  const float4* wr = (const float4*)w;
  const float4 wa = wr[t], wb = wr[t + 256];
  uint2 ua, ub;
  ua.x = (u32)f2bf(a.x*r*wa.x) | ((u32)f2bf(a.y*r*wa.y) << 16);
  ua.y = (u32)f2bf(a.z*r*wa.z) | ((u32)f2bf(a.w*r*wa.w) << 16);
  ub.x = (u32)f2bf(b.x*r*wb.x) | ((u32)f2bf(b.y*r*wb.y) << 16);
  ub.y = (u32)f2bf(b.z*r*wb.z) | ((u32)f2bf(b.w*r*wb.w) << 16);
  *(uint2*)(out + (long)s * DMODEL + 4 * t) = ua;
  *(uint2*)(out + (long)s * DMODEL + 1024 + 4 * t) = ub;
}

// ------ fused: x += p0 + p1 (split-K partials), then RMSNorm with weight w ------
__global__ void k_red2rms(float* __restrict__ x, const float* __restrict__ p0,
                          const float* __restrict__ p1, const float* __restrict__ w,
                          u16* __restrict__ out){
  const int s = blockIdx.x, t = threadIdx.x;
  const long base = (long)s * DMODEL;
  float4 a = ((const float4*)(x + base))[t];
  float4 b = ((const float4*)(x + base))[t + 256];
  const float4 a0 = ((const float4*)(p0 + base))[t];
  const float4 b0 = ((const float4*)(p0 + base))[t + 256];
  const float4 a1 = ((const float4*)(p1 + base))[t];
  const float4 b1 = ((const float4*)(p1 + base))[t + 256];
  a.x += a0.x + a1.x; a.y += a0.y + a1.y; a.z += a0.z + a1.z; a.w += a0.w + a1.w;
  b.x += b0.x + b1.x; b.y += b0.y + b1.y; b.z += b0.z + b1.z; b.w += b0.w + b1.w;
  ((float4*)(x + base))[t] = a;
  ((float4*)(x + base))[t + 256] = b;
  float ss = a.x*a.x + a.y*a.y + a.z*a.z + a.w*a.w
           + b.x*b.x + b.y*b.y + b.z*b.z + b.w*b.w;
  #pragma unroll
  for (int off = 32; off > 0; off >>= 1) ss += __shfl_down(ss, off, 64);
  __shared__ float part[4];
  if ((t & 63) == 0) part[t >> 6] = ss;
  __syncthreads();
  const float r = rsqrtf((part[0] + part[1] + part[2] + part[3]) * (1.f / 2048.f) + EPSI);
  const float4* wr = (const float4*)w;
  const float4 wa = wr[t], wb = wr[t + 256];
  uint2 ua, ub;
  ua.x = (u32)f2bf(a.x*r*wa.x) | ((u32)f2bf(a.y*r*wa.y) << 16);
  ua.y = (u32)f2bf(a.z*r*wa.z) | ((u32)f2bf(a.w*r*wa.w) << 16);
  ub.x = (u32)f2bf(b.x*r*wb.x) | ((u32)f2bf(b.y*r*wb.y) << 16);
  ub.y = (u32)f2bf(b.z*r*wb.z) | ((u32)f2bf(b.w*r*wb.w) << 16);
  *(uint2*)(out + base + 4 * t) = ua;
  *(uint2*)(out + base + 1024 + 4 * t) = ub;
}

// -------------------- weight convert + transpose: W f32[K][N] -> Wt bf16[N][K] ---
__global__ __launch_bounds__(256) void k_convT(const float* __restrict__ W,
                                               u16* __restrict__ Wt, int N, int K){
  const int n0 = blockIdx.x * 64, k0 = blockIdx.y * 64;
  const int t = threadIdx.x;
  __shared__ u16 T[64][72];    // [n][k], padded
  const int r = t >> 4, c = (t & 15) << 2;
  #pragma unroll
  for (int p = 0; p < 4; ++p){
    const int k = p * 16 + r;
    const float4 v = *(const float4*)(W + (long)(k0 + k) * N + n0 + c);
    T[c + 0][k] = f2bf(v.x);
    T[c + 1][k] = f2bf(v.y);
    T[c + 2][k] = f2bf(v.z);
    T[c + 3][k] = f2bf(v.w);
  }
  __syncthreads();
  const int nr = t >> 3, kc = (t & 7) << 3;
  #pragma unroll
  for (int p = 0; p < 2; ++p){
    const int n = p * 32 + nr;
    *(uint4*)(Wt + (long)(n0 + n) * K + k0 + kc) = *(const uint4*)(&T[n][kc]);
  }
}

// -------- convT for mlp_in: gate/up INTERLEAVED dest rows (256-row groups) -------
__global__ __launch_bounds__(256) void k_convTmi(const float* __restrict__ W,
                                                 u16* __restrict__ Wt, int N, int K){
  const int n0 = blockIdx.x * 64, k0 = blockIdx.y * 64;
  const int t = threadIdx.x;
  __shared__ u16 T[64][72];
  const int r = t >> 4, c = (t & 15) << 2;
  #pragma unroll
  for (int p = 0; p < 4; ++p){
    const int k = p * 16 + r;
    const float4 v = *(const float4*)(W + (long)(k0 + k) * N + n0 + c);
    T[c + 0][k] = f2bf(v.x);
    T[c + 1][k] = f2bf(v.y);
    T[c + 2][k] = f2bf(v.z);
    T[c + 3][k] = f2bf(v.w);
  }
  __syncthreads();
  int drow0;
  if (n0 < PDIM) drow0 = (n0 >> 7) * 256 + (n0 & 127);
  else { const int m0 = n0 - PDIM; drow0 = (m0 >> 7) * 256 + 128 + (m0 & 127); }
  const int nr = t >> 3, kc = (t & 7) << 3;
  #pragma unroll
  for (int p = 0; p < 2; ++p){
    const int n = p * 32 + nr;
    *(uint4*)(Wt + (long)(drow0 + n) * K + k0 + kc) = *(const uint4*)(&T[n][kc]);
  }
}

// -------------------- V transpose: qkv V-part [S][4][128] -> vT [4][128][S] ------
__global__ __launch_bounds__(256) void k_transV(const u16* __restrict__ qkv,
                                                u16* __restrict__ vT){
  const int s0 = blockIdx.x * 64, d0 = blockIdx.y * 64, kh = blockIdx.z;
  const int t = threadIdx.x;
  __shared__ u16 T[64][72];   // [d][s]
  #pragma unroll
  for (int p = 0; p < 4; ++p){
    const int s = p * 16 + (t >> 4);
    const int c = (t & 15) * 4;
    const uint2 v = *(const uint2*)(qkv + (long)(s0 + s) * NQKV + DMODEL + 512 + kh * HDIM + d0 + c);
    T[c + 0][s] = (u16)(v.x);
    T[c + 1][s] = (u16)(v.x >> 16);
    T[c + 2][s] = (u16)(v.y);
    T[c + 3][s] = (u16)(v.y >> 16);
  }
  __syncthreads();
  #pragma unroll
  for (int p = 0; p < 2; ++p){
    const int d = p * 32 + (t >> 3);
    *(uint4*)(vT + ((long)kh * HDIM + d0 + d) * S_LEN + s0 + (t & 7) * 8) =
        *(const uint4*)(&T[d][(t & 7) * 8]);
  }
}

// -------------------- GEMM 128x128 (m97-structure, swizzled LDS, 1D mapped grid) --
template<int OUT_BF16, int RES>
__global__ __launch_bounds__(256) void k_gemm(const u16* __restrict__ A, const u16* __restrict__ Bt,
                                              void* C, const float* Rs,
                                              int M, int N, int K, int nbn, int G){
  int bm, bn;
  map_bmn(blockIdx.x, gridDim.x, nbn, G, bm, bn);
  const int t = threadIdx.x;
  const int w = t >> 6, lane = t & 63, l15 = lane & 15, g = lane >> 4;
  const int wr = w >> 1, wc = w & 1;
  __shared__ u16 As[4096];
  __shared__ u16 Bs[4096];
  f32x4 acc[4][4] = {};
  const long arow = (long)bm * 128;
  const long brow = (long)bn * 128;
  for (int kt = 0; kt < K; kt += 32){
    __syncthreads();
    #pragma unroll
    for (int c = 0; c < 2; ++c){
      const int q0 = ((w << 1) | c) << 6;
      const int q  = q0 | lane;
      stage_sw(A,  arow, K, kt, q, As + q0 * 8);
      stage_sw(Bt, brow, K, kt, q, Bs + q0 * 8);
    }
    __syncthreads();
    bf16x8 af[4], bfr[4];
    #pragma unroll
    for (int i = 0; i < 4; ++i)
      af[i] = lds_frag(As, wr * 64 + i * 16 + l15, g);
    #pragma unroll
    for (int i = 0; i < 4; ++i)
      bfr[i] = lds_frag(Bs, wc * 64 + i * 16 + l15, g);
    #pragma unroll
    for (int mi = 0; mi < 4; ++mi)
      #pragma unroll
      for (int ni = 0; ni < 4; ++ni)
        acc[mi][ni] = mfma16(af[mi], bfr[ni], acc[mi][ni]);
  }
  const int row0 = bm * 128 + wr * 64, col0 = bn * 128 + wc * 64;
  #pragma unroll
  for (int mi = 0; mi < 4; ++mi){
    #pragma unroll
    for (int ni = 0; ni < 4; ++ni){
      #pragma unroll
      for (int r = 0; r < 4; ++r){
        const long ri = row0 + mi * 16 + g * 4 + r;
        const long ci = col0 + ni * 16 + l15;
        float v = acc[mi][ni][r];
        if (RES) v += Rs[ri * N + ci];
        if (OUT_BF16) ((u16*)C)[ri * N + ci] = f2bf(v);
        else          ((float*)C)[ri * N + ci] = v;
      }
    }
  }
}

// -------------------- GEMM 128x128 split-K: blockIdx.y = K-half, fp32 partials ----
__global__ __launch_bounds__(256) void k_gemmsk(const u16* __restrict__ A,
                                                const u16* __restrict__ Bt,
                                                float* __restrict__ P,
                                                int M, int N, int K, int nbn, int G){
  const int ks = blockIdx.y;
  const int KH = K >> 1;
  A  += (long)ks * KH;
  Bt += (long)ks * KH;
  P  += (long)ks * M * N;
  int bm, bn;
  map_bmn(blockIdx.x, gridDim.x, nbn, G, bm, bn);
  const int t = threadIdx.x;
  const int w = t >> 6, lane = t & 63, l15 = lane & 15, g = lane >> 4;
  const int wr = w >> 1, wc = w & 1;
  __shared__ u16 As[4096];
  __shared__ u16 Bs[4096];
  f32x4 acc[4][4] = {};
  const long arow = (long)bm * 128;
  const long brow = (long)bn * 128;
  for (int kt = 0; kt < KH; kt += 32){
    __syncthreads();
    #pragma unroll
    for (int c = 0; c < 2; ++c){
      const int q0 = ((w << 1) | c) << 6;
      const int q  = q0 | lane;
      stage_sw(A,  arow, K, kt, q, As + q0 * 8);
      stage_sw(Bt, brow, K, kt, q, Bs + q0 * 8);
    }
    __syncthreads();
    bf16x8 af[4], bfr[4];
    #pragma unroll
    for (int i = 0; i < 4; ++i)
      af[i] = lds_frag(As, wr * 64 + i * 16 + l15, g);
    #pragma unroll
    for (int i = 0; i < 4; ++i)
      bfr[i] = lds_frag(Bs, wc * 64 + i * 16 + l15, g);
    #pragma unroll
    for (int mi = 0; mi < 4; ++mi)
      #pragma unroll
      for (int ni = 0; ni < 4; ++ni)
        acc[mi][ni] = mfma16(af[mi], bfr[ni], acc[mi][ni]);
  }
  const int row0 = bm * 128 + wr * 64, col0 = bn * 128 + wc * 64;
  #pragma unroll
  for (int mi = 0; mi < 4; ++mi){
    #pragma unroll
    for (int ni = 0; ni < 4; ++ni){
      #pragma unroll
      for (int r = 0; r < 4; ++r){
        const long ri = row0 + mi * 16 + g * 4 + r;
        const long ci = col0 + ni * 16 + l15;
        P[ri * N + ci] = acc[mi][ni][r];
      }
    }
  }
}

// ------- GEMM 128x256, 4 waves, per-wave 128x64 (0.375 LDS-reads/MFMA) -----------
// LDS-BW fix: per K-tile per CU (2 blocks resident) reads = 96 b128 = 1156 cyc
// < MFMA 1242 cyc -> MFMA-bound (prior 64x64-per-wave configs were LDS-capped
// at ~45%). 3 slots x 24 KB = 72 KB; __launch_bounds__(256,2) => 2 blocks/CU.
// Depth-2 prefetch, 6 loads/thread/tile, gate vmcnt(6) (=> t+1 landed), tail
// vmcnt(0). WAR: stage(t+2) hits slot (t-1)%3 whose reads drained by
// lgkmcnt(0) before iteration t-1's barrier; stage issues after that barrier.
template<int OUT_BF16>
__global__ __launch_bounds__(256, 2) void k_gemmY(const u16* __restrict__ A,
                                                  const u16* __restrict__ Bt,
                                                  void* C, int M, int N, int K,
                                                  int nbn, int G){
  __shared__ u16 L[36864];                   // slot s: A @ s*12288 (4096 u16), B @ +4096
  const int t = threadIdx.x;
  const int w = t >> 6, lane = t & 63, l15 = lane & 15, g = lane >> 4;
  int bm, bn;
  map_bmn(blockIdx.x, gridDim.x, nbn, G, bm, bn);
  const int NT = K >> 5;

  // hoisted staging addresses. A chunks q=t,t+256 (rows R0, R0+64);
  // B chunks q=t+i*256, i=0..3 (rows R0+64i).
  const int Rp0 = t >> 3;
  const int u0  = (t & 7) ^ (Rp0 & 7);
  const int R0  = (Rp0 << 1) | (u0 >> 2);
  const int kc0 = (u0 & 3) << 3;
  const u16* pA = A  + ((long)bm * 128 + R0) * (long)K + kc0;
  const u16* pB = Bt + ((long)bn * 256 + R0) * (long)K + kc0;
  const int w0 = (t & ~63) * 8;              // wave-uniform LDS chunk base (u16)

  auto stage = [&](int s){
    u16* dA = L + s * 12288;
    u16* dB = dA + 4096;
    GLOAD_LDS16(pA,                dA + w0);
    GLOAD_LDS16(pA + (long)64 * K, dA + 2048 + w0);
    GLOAD_LDS16(pB,                 dB + w0);
    GLOAD_LDS16(pB + (long)64 * K,  dB + 2048 + w0);
    GLOAD_LDS16(pB + (long)128 * K, dB + 4096 + w0);
    GLOAD_LDS16(pB + (long)192 * K, dB + 6144 + w0);
    pA += 32; pB += 32;
  };

  stage(0); stage(1);
  asm volatile("s_waitcnt vmcnt(6)" ::: "memory");   // tile 0 landed
  __builtin_amdgcn_s_barrier();

  f32x4 acc[8][4] = {};
  int slot = 0;
  for (int tt = 0; tt < NT; ++tt){
    const u16* sA = L + slot * 12288;
    const u16* sB = sA + 4096;
    bf16x8 af[8], bfr[4];
    #pragma unroll
    for (int mi = 0; mi < 8; ++mi)
      af[mi] = lds_frag(sA, mi * 16 + l15, g);
    #pragma unroll
    for (int ni = 0; ni < 4; ++ni)
      bfr[ni] = lds_frag(sB, w * 64 + ni * 16 + l15, g);
    if (tt + 2 < NT){
      int s2 = slot + 2; if (s2 >= 3) s2 -= 3;
      stage(s2);
    }
    asm volatile("s_waitcnt lgkmcnt(0)" ::: "memory");
    if (tt + 2 < NT)      asm volatile("s_waitcnt vmcnt(6)" ::: "memory");
    else if (tt + 1 < NT) asm volatile("s_waitcnt vmcnt(0)" ::: "memory");
    __builtin_amdgcn_s_barrier();
    __builtin_amdgcn_s_setprio(1);
    #pragma unroll
    for (int mi = 0; mi < 8; ++mi)
      #pragma unroll
      for (int ni = 0; ni < 4; ++ni)
        acc[mi][ni] = mfma16(af[mi], bfr[ni], acc[mi][ni]);
    __builtin_amdgcn_s_setprio(0);
    ++slot; if (slot == 3) slot = 0;
  }
  // ---- epilogue ----
  const int row0 = bm * 128, col0 = bn * 256 + w * 64;
  #pragma unroll
  for (int mi = 0; mi < 8; ++mi){
    #pragma unroll
    for (int ni = 0; ni < 4; ++ni){
      #pragma unroll
      for (int r = 0; r < 4; ++r){
        const long ri = row0 + mi * 16 + g * 4 + r;
        const long ci = col0 + ni * 16 + l15;
        const float v = acc[mi][ni][r];
        if (OUT_BF16) ((u16*)C)[ri * N + ci] = f2bf(v);
        else          ((float*)C)[ri * N + ci] = v;
      }
    }
  }
}

// ------- GEMM 128x256 + fused SwiGLU epilogue (mlp_in, interleaved weights) ------
// Waves 0,1 = gate cols (bn*128 + w*64 ..), waves 2,3 = matching up cols.
// Up waves park acc in LDS (64 KB of the 72 KB staging space, drained), gate
// waves combine silu(g)*u -> O[seq][PDIM].
__global__ __launch_bounds__(256, 2) void k_gemmYswi(const u16* __restrict__ A,
                                                     const u16* __restrict__ Bt,
                                                     u16* __restrict__ O,
                                                     int M, int K, int nbn, int G){
  __shared__ u16 L[36864];
  const int t = threadIdx.x;
  const int w = t >> 6, lane = t & 63, l15 = lane & 15, g = lane >> 4;
  int bm, bn;
  map_bmn(blockIdx.x, gridDim.x, nbn, G, bm, bn);
  const int NT = K >> 5;

  const int Rp0 = t >> 3;
  const int u0  = (t & 7) ^ (Rp0 & 7);
  const int R0  = (Rp0 << 1) | (u0 >> 2);
  const int kc0 = (u0 & 3) << 3;
  const u16* pA = A  + ((long)bm * 128 + R0) * (long)K + kc0;
  const u16* pB = Bt + ((long)bn * 256 + R0) * (long)K + kc0;
  const int w0 = (t & ~63) * 8;

  auto stage = [&](int s){
    u16* dA = L + s * 12288;
    u16* dB = dA + 4096;
    GLOAD_LDS16(pA,                dA + w0);
    GLOAD_LDS16(pA + (long)64 * K, dA + 2048 + w0);
    GLOAD_LDS16(pB,                 dB + w0);
    GLOAD_LDS16(pB + (long)64 * K,  dB + 2048 + w0);
    GLOAD_LDS16(pB + (long)128 * K, dB + 4096 + w0);
    GLOAD_LDS16(pB + (long)192 * K, dB + 6144 + w0);
    pA += 32; pB += 32;
  };

  stage(0); stage(1);
  asm volatile("s_waitcnt vmcnt(6)" ::: "memory");
  __builtin_amdgcn_s_barrier();

  f32x4 acc[8][4] = {};
  int slot = 0;
  for (int tt = 0; tt < NT; ++tt){
    const u16* sA = L + slot * 12288;
    const u16* sB = sA + 4096;
    bf16x8 af[8], bfr[4];
    #pragma unroll
    for (int mi = 0; mi < 8; ++mi)
      af[mi] = lds_frag(sA, mi * 16 + l15, g);
    #pragma unroll
    for (int ni = 0; ni < 4; ++ni)
      bfr[ni] = lds_frag(sB, w * 64 + ni * 16 + l15, g);
    if (tt + 2 < NT){
      int s2 = slot + 2; if (s2 >= 3) s2 -= 3;
      stage(s2);
    }
    asm volatile("s_waitcnt lgkmcnt(0)" ::: "memory");
    if (tt + 2 < NT)      asm volatile("s_waitcnt vmcnt(6)" ::: "memory");
    else if (tt + 1 < NT) asm volatile("s_waitcnt vmcnt(0)" ::: "memory");
    __builtin_amdgcn_s_barrier();
    __builtin_amdgcn_s_setprio(1);
    #pragma unroll
    for (int mi = 0; mi < 8; ++mi)
      #pragma unroll
      for (int ni = 0; ni < 4; ++ni)
        acc[mi][ni] = mfma16(af[mi], bfr[ni], acc[mi][ni]);
    __builtin_amdgcn_s_setprio(0);
    ++slot; if (slot == 3) slot = 0;
  }
  // ---- fused SwiGLU epilogue ----
  __syncthreads();
  float* U = (float*)L;                      // 2 x 32 KB = 64 KB of 72 KB
  if (w >= 2){                               // up waves park acc
    const int base = (w - 2) * 8192;         // 128x64 fp32
    #pragma unroll
    for (int mi = 0; mi < 8; ++mi)
      #pragma unroll
      for (int ni = 0; ni < 4; ++ni)
        #pragma unroll
        for (int r = 0; r < 4; ++r)
          U[base + (mi * 16 + g * 4 + r) * 64 + ni * 16 + l15] = acc[mi][ni][r];
  }
  __syncthreads();
  if (w < 2){                                // gate waves combine + store
    const int base = w * 8192;
    #pragma unroll
    for (int mi = 0; mi < 8; ++mi){
      #pragma unroll
      for (int ni = 0; ni < 4; ++ni){
        #pragma unroll
        for (int r = 0; r < 4; ++r){
          const float gv = acc[mi][ni][r];
          const float uv = U[base + (mi * 16 + g * 4 + r) * 64 + ni * 16 + l15];
          const float ov = gv / (1.f + __expf(-gv)) * uv;
          const long ri = bm * 128 + mi * 16 + g * 4 + r;
          const int ci = bn * 128 + w * 64 + ni * 16 + l15;
          O[ri * PDIM + ci] = f2bf(ov);
        }
      }
    }
  }
}

// -------------------- RoPE in-place on bf16 qkv --------------------
__global__ void k_rope(u16* __restrict__ qkv){
  const int idx = blockIdx.x * 256 + threadIdx.x;   // S * 20 * 64
  const int i = idx & 63;
  const int head = (idx >> 6) % 20;
  const int s = idx / (64 * 20);
  const long base = (long)s * NQKV + (head < NHQ ? head * HDIM : DMODEL + (head - NHQ) * HDIM);
  u32* p = (u32*)(qkv + base + 2 * i);
  const u32 v = *p;
  const float x0 = bf2f((u16)(v & 0xffffu)), x1 = bf2f((u16)(v >> 16));
  const float ang = (float)s * exp2f(-0.29580575889569023f * (float)i);
  float sn, cs;
  sincosf(ang, &sn, &cs);
  const float y0 = x0 * cs - x1 * sn;
  const float y1 = x0 * sn + x1 * cs;
  *p = (u32)f2bf(y0) | ((u32)f2bf(y1) << 16);
}

// ------------- Flash attention (R13-proven): XCD-pinned kh + LPT ordering --------
__global__ __launch_bounds__(256) void k_attn(const u16* __restrict__ qkv,
                                              const u16* __restrict__ vT,
                                              u16* __restrict__ o){
  const int id = blockIdx.x;
  const int xcd = id & 7, j = id >> 3;
  const int kh = xcd >> 1;
  const int h  = (kh << 2) + ((xcd & 1) << 1) + (j & 1);
  const int qb = 31 - (j >> 1);
  const int t = threadIdx.x, w = t >> 6, lane = t & 63, l15 = lane & 15, g = lane >> 4;
  __shared__ u16 Ks[2][8192];
  __shared__ u16 Vs[2][8192];
  __shared__ u16 Ps[4][16 * 72];
  const int q0 = qb * 64 + w * 16;
  bf16x8 aq[4];
  #pragma unroll
  for (int d0 = 0; d0 < 4; ++d0)
    aq[d0] = ld8(qkv + (long)(q0 + l15) * NQKV + h * HDIM + d0 * 32 + g * 8);
  f32x4 acc_o[8] = {};
  float mst[4], lst[4];
  #pragma unroll
  for (int r = 0; r < 4; ++r){ mst[r] = -1e30f; lst[r] = 0.f; }
  const float scale = 0.08838834764831843f;

  auto stageK = [&](int kt, int b){
    #pragma unroll
    for (int p = 0; p < 4; ++p){
      const int q = p * 256 + t;
      const int r = q >> 4, u = q & 15;
      const u16* gp = qkv + (long)(kt * 64 + r) * NQKV + DMODEL + kh * HDIM + ((u ^ (r & 15)) << 3);
      GLOAD_LDS16(gp, Ks[b] + (p * 256 + (t & ~63)) * 8);
    }
  };
  auto stageV = [&](int kt, int b){
    #pragma unroll
    for (int p = 0; p < 4; ++p){
      const int q = p * 256 + t;
      const int r = q >> 3, u = q & 7;
      const u16* gp = vT + ((long)kh * HDIM + r) * S_LEN + kt * 64 + ((u ^ (r & 7)) << 3);
      GLOAD_LDS16(gp, Vs[b] + (p * 256 + (t & ~63)) * 8);
    }
  };

  const int nkt = qb + 1;
  stageK(0, 0); stageV(0, 0);
  for (int kt = 0; kt < nkt; ++kt){
    const int kv0 = kt << 6;
    __builtin_amdgcn_s_barrier();            // (a) prev reads drained -> DMA may overwrite
    if (kt + 1 < nkt){
      stageK(kt + 1, (kt + 1) & 1);
      stageV(kt + 1, (kt + 1) & 1);
      asm volatile("s_waitcnt vmcnt(8)" ::: "memory");
    } else {
      asm volatile("s_waitcnt vmcnt(0)" ::: "memory");
    }
    __builtin_amdgcn_s_barrier();            // (b) tile kt globally visible
    const u16* K_ = Ks[kt & 1];
    const u16* V_ = Vs[kt & 1];
    // ---- S = Q K^T ----
    f32x4 sacc[4] = {};
    #pragma unroll
    for (int d0 = 0; d0 < 4; ++d0){
      #pragma unroll
      for (int j2 = 0; j2 < 4; ++j2){
        const bf16x8 bk = ld8(K_ + (j2 * 16 + l15) * 128 + ((((d0 << 2) | g) ^ l15) << 3));
        sacc[j2] = mfma16(aq[d0], bk, sacc[j2]);
      }
    }
    // ---- mask + online softmax (rows in 16-lane groups) ----
    float p[4][4], scl[4];
    #pragma unroll
    for (int r = 0; r < 4; ++r){
      const int qrow = q0 + g * 4 + r;
      float mx = -1e30f;
      #pragma unroll
      for (int j2 = 0; j2 < 4; ++j2){
        float sv = sacc[j2][r] * scale;
        sv = (kv0 + j2 * 16 + l15 <= qrow) ? sv : -1e30f;
        p[j2][r] = sv;
        mx = fmaxf(mx, sv);
      }
      #pragma unroll
      for (int off = 1; off < 16; off <<= 1) mx = fmaxf(mx, __shfl_xor(mx, off, 64));
      const float mnew = fmaxf(mst[r], mx);
      scl[r] = __expf(mst[r] - mnew);
      float rs = 0.f;
      #pragma unroll
      for (int j2 = 0; j2 < 4; ++j2){ p[j2][r] = __expf(p[j2][r] - mnew); rs += p[j2][r]; }
      #pragma unroll
      for (int off = 1; off < 16; off <<= 1) rs += __shfl_xor(rs, off, 64);
      lst[r] = lst[r] * scl[r] + rs;
      mst[r] = mnew;
    }
    #pragma unroll
    for (int n = 0; n < 8; ++n)
      #pragma unroll
      for (int r = 0; r < 4; ++r)
        acc_o[n][r] *= scl[r];
    // ---- P -> LDS (per-wave), then PV ----
    #pragma unroll
    for (int j2 = 0; j2 < 4; ++j2)
      #pragma unroll
      for (int r = 0; r < 4; ++r)
        Ps[w][(g * 4 + r) * 72 + j2 * 16 + l15] = f2bf(p[j2][r]);
    #pragma unroll
    for (int kk = 0; kk < 2; ++kk){
      const bf16x8 pa = ld8(Ps[w] + l15 * 72 + kk * 32 + g * 8);
      #pragma unroll
      for (int n = 0; n < 8; ++n){
        const int row = n * 16 + l15;
        const bf16x8 bv = ld8(V_ + row * 64 + ((((kk << 2) | g) ^ (l15 & 7)) << 3));
        acc_o[n] = mfma16(pa, bv, acc_o[n]);
      }
    }
    asm volatile("s_waitcnt lgkmcnt(0)" ::: "memory");   // drain my LDS reads (WAR)
  }
  #pragma unroll
  for (int n = 0; n < 8; ++n){
    #pragma unroll
    for (int r = 0; r < 4; ++r){
      const float ov = acc_o[n][r] / lst[r];
      o[(long)(q0 + g * 4 + r) * DMODEL + h * HDIM + n * 16 + l15] = f2bf(ov);
    }
  }
}

// -------------------- launch --------------------
extern "C" void kernel_launch(void* const* d_in, const int* in_sizes, int n_in,
                              void* d_out, int out_size, void* d_ws, size_t ws_size,
                              hipStream_t stream){
  const int*   tokens       = (const int*)d_in[0];
  const float* embed        = (const float*)d_in[1];
  const float* attn_norm_w  = (const float*)d_in[2];
  const float* qkv_w        = (const float*)d_in[3];
  const float* attn_out_w   = (const float*)d_in[4];
  const float* mlp_norm_w   = (const float*)d_in[5];
  const float* mlp_in_w     = (const float*)d_in[6];
  const float* mlp_out_w    = (const float*)d_in[7];
  const float* final_norm_w = (const float*)d_in[8];
  const float* lm_head_w    = (const float*)d_in[9];

  char* ws = (char*)d_ws;
  float* xf  = (float*)(ws);                    // 16.78 MB residual (fp32)
  u16* hbf   = (u16*)(ws + 16777216);           //  8.39 MB normed activations
  u16* qkvb  = (u16*)(ws + 25165824);           // 12.58 MB qkv
  u16* obf   = (u16*)(ws + 37748736);           //  8.39 MB attn out
  u16* gub   = (u16*)(ws + 46137344);           // 67.11 MB (fp32 partials region)
  u16* hb2   = (u16*)(ws + 113246208);          // 33.55 MB silu(g)*u
  u16* wbuf  = (u16*)(ws + 146800640);          // 131.07 MB transposed bf16 weights
  u16* vTb   = (u16*)(ws + 277872640);          //  2.10 MB transposed V
  float* pp  = (float*)gub;                     // 33.55 MB: 2 x [2048x2048] fp32 partials

  k_embed<<<S_LEN, 256, 0, stream>>>(tokens, embed, xf);
  k_rmsnorm<<<S_LEN, 256, 0, stream>>>(xf, attn_norm_w, hbf);
  for (int l = 0; l < 2; ++l){
    k_convT<<<dim3(NQKV/64, DMODEL/64), 256, 0, stream>>>(
        qkv_w + (long)l * DMODEL * NQKV, wbuf, NQKV, DMODEL);
    k_gemm<1,0><<<(S_LEN/128) * (NQKV/128), 256, 0, stream>>>(
        hbf, wbuf, qkvb, nullptr, S_LEN, NQKV, DMODEL, NQKV/128, 4);
    k_rope<<<(S_LEN * 20 * 64) / 256, 256, 0, stream>>>(qkvb);
    k_transV<<<dim3(S_LEN/64, 2, 4), 256, 0, stream>>>(qkvb, vTb);
    k_attn<<<512, 256, 0, stream>>>(qkvb, vTb, obf);
    k_convT<<<dim3(DMODEL/64, DMODEL/64), 256, 0, stream>>>(
        attn_out_w + (long)l * DMODEL * DMODEL, wbuf, DMODEL, DMODEL);
    k_gemm<0,1><<<(S_LEN/128) * (DMODEL/128), 256, 0, stream>>>(
        obf, wbuf, xf, xf, S_LEN, DMODEL, DMODEL, DMODEL/128, 4);
    k_rmsnorm<<<S_LEN, 256, 0, stream>>>(xf, mlp_norm_w + (long)l * DMODEL, hbf);
    k_convTmi<<<dim3((2*PDIM)/64, DMODEL/64), 256, 0, stream>>>(
        mlp_in_w + (long)l * DMODEL * 2 * PDIM, wbuf, 2*PDIM, DMODEL);
    k_gemmYswi<<<(S_LEN/128) * ((2*PDIM)/256), 256, 0, stream>>>(
        hbf, wbuf, hb2, S_LEN, DMODEL, (2*PDIM)/256, 4);
    k_convT<<<dim3(DMODEL/64, PDIM/64), 256, 0, stream>>>(
        mlp_out_w + (long)l * PDIM * DMODEL, wbuf, DMODEL, PDIM);
    k_gemmsk<<<dim3((S_LEN/128) * (DMODEL/128), 2), 256, 0, stream>>>(
        hb2, wbuf, pp, S_LEN, DMODEL, PDIM, DMODEL/128, 2);
    // fused: x += p0 + p1, then RMSNorm with the NEXT norm weight
    k_red2rms<<<S_LEN, 256, 0, stream>>>(
        xf, pp, pp + (long)S_LEN * DMODEL,
        (l == 0) ? (attn_norm_w + DMODEL) : final_norm_w, hbf);
  }
  k_convT<<<dim3(VOCAB/64, DMODEL/64), 256, 0, stream>>>(lm_head_w, wbuf, VOCAB, DMODEL);
  k_gemmY<0><<<(S_LEN/128) * (VOCAB/256), 256, 0, stream>>>(
      hbf, wbuf, (float*)d_out, S_LEN, VOCAB, DMODEL, VOCAB/256, 4);
}

// Round 17
// 1344.968 us; speedup vs baseline: 1.0424x; 1.0424x over previous
//
#include <hip/hip_runtime.h>
#include <math.h>

#define S_LEN 2048
#define DMODEL 2048
#define NHQ 16
#define NHK 4
#define HDIM 128
#define PDIM 8192
#define VOCAB 32000
#define NQKV 3072          // D + 2*HK*HD
#define EPSI 1e-5f

typedef unsigned short u16;
typedef unsigned int u32;
typedef __bf16 bf16x8 __attribute__((ext_vector_type(8)));
typedef float f32x4 __attribute__((ext_vector_type(4)));

__device__ __forceinline__ u16 f2bf(float f){
  u32 u = __builtin_bit_cast(u32, f);
  u += 0x7fffu + ((u >> 16) & 1u);   // RNE
  return (u16)(u >> 16);
}
__device__ __forceinline__ float bf2f(u16 h){
  u32 u = ((u32)h) << 16;
  return __builtin_bit_cast(float, u);
}
__device__ __forceinline__ bf16x8 ld8(const u16* p){
  return __builtin_bit_cast(bf16x8, *(const uint4*)p);
}
__device__ __forceinline__ f32x4 mfma16(bf16x8 a, bf16x8 b, f32x4 c){
  return __builtin_amdgcn_mfma_f32_16x16x32_bf16(a, b, c, 0, 0, 0);
}

#define GLOAD_LDS16(gp, lp) __builtin_amdgcn_global_load_lds( \
    (__attribute__((address_space(1))) void*)(gp), \
    (__attribute__((address_space(3))) void*)(lp), 16, 0, 0)

// Swizzled LDS tile layout: [Rows][32k] bf16 stored as row-PAIRS; line Rp=R>>1
// holds rows {2Rp,2Rp+1} x 32 k = 128 B = 8 slots of 16 B, slot XOR (Rp&7).
// gload_lds dest LINEAR; permutation applied to per-lane GLOBAL source.
// 0 bank conflicts measured (R3-R16).
__device__ __forceinline__ bf16x8 lds_frag(const u16* Lb, int R, int g){
  const int Rp = R >> 1;
  const int s8 = (((R & 1) << 2) | g) ^ (Rp & 7);
  return ld8(Lb + Rp * 64 + s8 * 8);
}
__device__ __forceinline__ void stage_sw(const u16* base, long row0, int kstride, int kt,
                                         int q, u16* Ldst_waveuniform){
  const int Rp = q >> 3;
  const int u = (q & 7) ^ (Rp & 7);
  const int R = (Rp << 1) | (u >> 2);
  const u16* gp = base + (row0 + R) * (long)kstride + kt + ((u & 3) << 3);
  GLOAD_LDS16(gp, Ldst_waveuniform);
}

// XCD-contiguous, bm-grouped block mapping.
__device__ __forceinline__ void map_bmn(int id0, int nwg, int nbn, int G,
                                        int& bm, int& bn){
  const int cpx = nwg >> 3;               // nwg % 8 == 0 at all call sites
  const int id = (id0 & 7) * cpx + (id0 >> 3);
  const int bmi = id % G;
  const int r2 = id / G;
  bn = r2 % nbn;
  bm = (r2 / nbn) * G + bmi;
}

// -------------------- embed gather --------------------
__global__ void k_embed(const int* __restrict__ tok, const float* __restrict__ emb,
                        float* __restrict__ x){
  const int s = blockIdx.x, t = threadIdx.x;
  const long r = tok[s];
  const float4* src = (const float4*)(emb + r * DMODEL);
  float4* dst = (float4*)(x + (long)s * DMODEL);
  dst[t] = src[t];
  dst[t + 256] = src[t + 256];
}

// -------------------- RMSNorm: fp32 in -> bf16 out --------------------
__global__ void k_rmsnorm(const float* __restrict__ x, const float* __restrict__ w,
                          u16* __restrict__ out){
  const int s = blockIdx.x, t = threadIdx.x;
  const float4* xr = (const float4*)(x + (long)s * DMODEL);
  const float4 a = xr[t], b = xr[t + 256];
  float ss = a.x*a.x + a.y*a.y + a.z*a.z + a.w*a.w
           + b.x*b.x + b.y*b.y + b.z*b.z + b.w*b.w;
  #pragma unroll
  for (int off = 32; off > 0; off >>= 1) ss += __shfl_down(ss, off, 64);
  __shared__ float part[4];
  if ((t & 63) == 0) part[t >> 6] = ss;
  __syncthreads();
  const float r = rsqrtf((part[0] + part[1] + part[2] + part[3]) * (1.f / 2048.f) + EPSI);
  const float4* wr = (const float4*)w;
  const float4 wa = wr[t], wb = wr[t + 256];
  uint2 ua, ub;
  ua.x = (u32)f2bf(a.x*r*wa.x) | ((u32)f2bf(a.y*r*wa.y) << 16);
  ua.y = (u32)f2bf(a.z*r*wa.z) | ((u32)f2bf(a.w*r*wa.w) << 16);
  ub.x = (u32)f2bf(b.x*r*wb.x) | ((u32)f2bf(b.y*r*wb.y) << 16);
  ub.y = (u32)f2bf(b.z*r*wb.z) | ((u32)f2bf(b.w*r*wb.w) << 16);
  *(uint2*)(out + (long)s * DMODEL + 4 * t) = ua;
  *(uint2*)(out + (long)s * DMODEL + 1024 + 4 * t) = ub;
}

// ------ fused: x += p0 + p1 (split-K partials), then RMSNorm with weight w ------
__global__ void k_red2rms(float* __restrict__ x, const float* __restrict__ p0,
                          const float* __restrict__ p1, const float* __restrict__ w,
                          u16* __restrict__ out){
  const int s = blockIdx.x, t = threadIdx.x;
  const long base = (long)s * DMODEL;
  float4 a = ((const float4*)(x + base))[t];
  float4 b = ((const float4*)(x + base))[t + 256];
  const float4 a0 = ((const float4*)(p0 + base))[t];
  const float4 b0 = ((const float4*)(p0 + base))[t + 256];
  const float4 a1 = ((const float4*)(p1 + base))[t];
  const float4 b1 = ((const float4*)(p1 + base))[t + 256];
  a.x += a0.x + a1.x; a.y += a0.y + a1.y; a.z += a0.z + a1.z; a.w += a0.w + a1.w;
  b.x += b0.x + b1.x; b.y += b0.y + b1.y; b.z += b0.z + b1.z; b.w += b0.w + b1.w;
  ((float4*)(x + base))[t] = a;
  ((float4*)(x + base))[t + 256] = b;
  float ss = a.x*a.x + a.y*a.y + a.z*a.z + a.w*a.w
           + b.x*b.x + b.y*b.y + b.z*b.z + b.w*b.w;
  #pragma unroll
  for (int off = 32; off > 0; off >>= 1) ss += __shfl_down(ss, off, 64);
  __shared__ float part[4];
  if ((t & 63) == 0) part[t >> 6] = ss;
  __syncthreads();
  const float r = rsqrtf((part[0] + part[1] + part[2] + part[3]) * (1.f / 2048.f) + EPSI);
  const float4* wr = (const float4*)w;
  const float4 wa = wr[t], wb = wr[t + 256];
  uint2 ua, ub;
  ua.x = (u32)f2bf(a.x*r*wa.x) | ((u32)f2bf(a.y*r*wa.y) << 16);
  ua.y = (u32)f2bf(a.z*r*wa.z) | ((u32)f2bf(a.w*r*wa.w) << 16);
  ub.x = (u32)f2bf(b.x*r*wb.x) | ((u32)f2bf(b.y*r*wb.y) << 16);
  ub.y = (u32)f2bf(b.z*r*wb.z) | ((u32)f2bf(b.w*r*wb.w) << 16);
  *(uint2*)(out + base + 4 * t) = ua;
  *(uint2*)(out + base + 1024 + 4 * t) = ub;
}

// -------------------- weight convert + transpose: W f32[K][N] -> Wt bf16[N][K] ---
__global__ __launch_bounds__(256) void k_convT(const float* __restrict__ W,
                                               u16* __restrict__ Wt, int N, int K){
  const int n0 = blockIdx.x * 64, k0 = blockIdx.y * 64;
  const int t = threadIdx.x;
  __shared__ u16 T[64][72];    // [n][k], padded
  const int r = t >> 4, c = (t & 15) << 2;
  #pragma unroll
  for (int p = 0; p < 4; ++p){
    const int k = p * 16 + r;
    const float4 v = *(const float4*)(W + (long)(k0 + k) * N + n0 + c);
    T[c + 0][k] = f2bf(v.x);
    T[c + 1][k] = f2bf(v.y);
    T[c + 2][k] = f2bf(v.z);
    T[c + 3][k] = f2bf(v.w);
  }
  __syncthreads();
  const int nr = t >> 3, kc = (t & 7) << 3;
  #pragma unroll
  for (int p = 0; p < 2; ++p){
    const int n = p * 32 + nr;
    *(uint4*)(Wt + (long)(n0 + n) * K + k0 + kc) = *(const uint4*)(&T[n][kc]);
  }
}

// -------- convT for mlp_in: gate/up INTERLEAVED dest rows (256-row groups) -------
__global__ __launch_bounds__(256) void k_convTmi(const float* __restrict__ W,
                                                 u16* __restrict__ Wt, int N, int K){
  const int n0 = blockIdx.x * 64, k0 = blockIdx.y * 64;
  const int t = threadIdx.x;
  __shared__ u16 T[64][72];
  const int r = t >> 4, c = (t & 15) << 2;
  #pragma unroll
  for (int p = 0; p < 4; ++p){
    const int k = p * 16 + r;
    const float4 v = *(const float4*)(W + (long)(k0 + k) * N + n0 + c);
    T[c + 0][k] = f2bf(v.x);
    T[c + 1][k] = f2bf(v.y);
    T[c + 2][k] = f2bf(v.z);
    T[c + 3][k] = f2bf(v.w);
  }
  __syncthreads();
  int drow0;
  if (n0 < PDIM) drow0 = (n0 >> 7) * 256 + (n0 & 127);
  else { const int m0 = n0 - PDIM; drow0 = (m0 >> 7) * 256 + 128 + (m0 & 127); }
  const int nr = t >> 3, kc = (t & 7) << 3;
  #pragma unroll
  for (int p = 0; p < 2; ++p){
    const int n = p * 32 + nr;
    *(uint4*)(Wt + (long)(drow0 + n) * K + k0 + kc) = *(const uint4*)(&T[n][kc]);
  }
}

// -------------------- V transpose: qkv V-part [S][4][128] -> vT [4][128][S] ------
__global__ __launch_bounds__(256) void k_transV(const u16* __restrict__ qkv,
                                                u16* __restrict__ vT){
  const int s0 = blockIdx.x * 64, d0 = blockIdx.y * 64, kh = blockIdx.z;
  const int t = threadIdx.x;
  __shared__ u16 T[64][72];   // [d][s]
  #pragma unroll
  for (int p = 0; p < 4; ++p){
    const int s = p * 16 + (t >> 4);
    const int c = (t & 15) * 4;
    const uint2 v = *(const uint2*)(qkv + (long)(s0 + s) * NQKV + DMODEL + 512 + kh * HDIM + d0 + c);
    T[c + 0][s] = (u16)(v.x);
    T[c + 1][s] = (u16)(v.x >> 16);
    T[c + 2][s] = (u16)(v.y);
    T[c + 3][s] = (u16)(v.y >> 16);
  }
  __syncthreads();
  #pragma unroll
  for (int p = 0; p < 2; ++p){
    const int d = p * 32 + (t >> 3);
    *(uint4*)(vT + ((long)kh * HDIM + d0 + d) * S_LEN + s0 + (t & 7) * 8) =
        *(const uint4*)(&T[d][(t & 7) * 8]);
  }
}

// -------------------- GEMM 128x128 (m97-structure, swizzled LDS, 1D mapped grid) --
template<int OUT_BF16, int RES>
__global__ __launch_bounds__(256) void k_gemm(const u16* __restrict__ A, const u16* __restrict__ Bt,
                                              void* C, const float* Rs,
                                              int M, int N, int K, int nbn, int G){
  int bm, bn;
  map_bmn(blockIdx.x, gridDim.x, nbn, G, bm, bn);
  const int t = threadIdx.x;
  const int w = t >> 6, lane = t & 63, l15 = lane & 15, g = lane >> 4;
  const int wr = w >> 1, wc = w & 1;
  __shared__ u16 As[4096];
  __shared__ u16 Bs[4096];
  f32x4 acc[4][4] = {};
  const long arow = (long)bm * 128;
  const long brow = (long)bn * 128;
  for (int kt = 0; kt < K; kt += 32){
    __syncthreads();
    #pragma unroll
    for (int c = 0; c < 2; ++c){
      const int q0 = ((w << 1) | c) << 6;
      const int q  = q0 | lane;
      stage_sw(A,  arow, K, kt, q, As + q0 * 8);
      stage_sw(Bt, brow, K, kt, q, Bs + q0 * 8);
    }
    __syncthreads();
    bf16x8 af[4], bfr[4];
    #pragma unroll
    for (int i = 0; i < 4; ++i)
      af[i] = lds_frag(As, wr * 64 + i * 16 + l15, g);
    #pragma unroll
    for (int i = 0; i < 4; ++i)
      bfr[i] = lds_frag(Bs, wc * 64 + i * 16 + l15, g);
    #pragma unroll
    for (int mi = 0; mi < 4; ++mi)
      #pragma unroll
      for (int ni = 0; ni < 4; ++ni)
        acc[mi][ni] = mfma16(af[mi], bfr[ni], acc[mi][ni]);
  }
  const int row0 = bm * 128 + wr * 64, col0 = bn * 128 + wc * 64;
  #pragma unroll
  for (int mi = 0; mi < 4; ++mi){
    #pragma unroll
    for (int ni = 0; ni < 4; ++ni){
      #pragma unroll
      for (int r = 0; r < 4; ++r){
        const long ri = row0 + mi * 16 + g * 4 + r;
        const long ci = col0 + ni * 16 + l15;
        float v = acc[mi][ni][r];
        if (RES) v += Rs[ri * N + ci];
        if (OUT_BF16) ((u16*)C)[ri * N + ci] = f2bf(v);
        else          ((float*)C)[ri * N + ci] = v;
      }
    }
  }
}

// -------------------- GEMM 128x128 split-K: blockIdx.y = K-half, fp32 partials ----
__global__ __launch_bounds__(256) void k_gemmsk(const u16* __restrict__ A,
                                                const u16* __restrict__ Bt,
                                                float* __restrict__ P,
                                                int M, int N, int K, int nbn, int G){
  const int ks = blockIdx.y;
  const int KH = K >> 1;
  A  += (long)ks * KH;
  Bt += (long)ks * KH;
  P  += (long)ks * M * N;
  int bm, bn;
  map_bmn(blockIdx.x, gridDim.x, nbn, G, bm, bn);
  const int t = threadIdx.x;
  const int w = t >> 6, lane = t & 63, l15 = lane & 15, g = lane >> 4;
  const int wr = w >> 1, wc = w & 1;
  __shared__ u16 As[4096];
  __shared__ u16 Bs[4096];
  f32x4 acc[4][4] = {};
  const long arow = (long)bm * 128;
  const long brow = (long)bn * 128;
  for (int kt = 0; kt < KH; kt += 32){
    __syncthreads();
    #pragma unroll
    for (int c = 0; c < 2; ++c){
      const int q0 = ((w << 1) | c) << 6;
      const int q  = q0 | lane;
      stage_sw(A,  arow, K, kt, q, As + q0 * 8);
      stage_sw(Bt, brow, K, kt, q, Bs + q0 * 8);
    }
    __syncthreads();
    bf16x8 af[4], bfr[4];
    #pragma unroll
    for (int i = 0; i < 4; ++i)
      af[i] = lds_frag(As, wr * 64 + i * 16 + l15, g);
    #pragma unroll
    for (int i = 0; i < 4; ++i)
      bfr[i] = lds_frag(Bs, wc * 64 + i * 16 + l15, g);
    #pragma unroll
    for (int mi = 0; mi < 4; ++mi)
      #pragma unroll
      for (int ni = 0; ni < 4; ++ni)
        acc[mi][ni] = mfma16(af[mi], bfr[ni], acc[mi][ni]);
  }
  const int row0 = bm * 128 + wr * 64, col0 = bn * 128 + wc * 64;
  #pragma unroll
  for (int mi = 0; mi < 4; ++mi){
    #pragma unroll
    for (int ni = 0; ni < 4; ++ni){
      #pragma unroll
      for (int r = 0; r < 4; ++r){
        const long ri = row0 + mi * 16 + g * 4 + r;
        const long ci = col0 + ni * 16 + l15;
        P[ri * N + ci] = acc[mi][ni][r];
      }
    }
  }
}

// -------------------- GEMM 256x256, 16 waves, 4-slot LDS, depth-3 (R13/R15 best) --
template<int OUT_BF16>
__global__ __launch_bounds__(1024, 4) void k_gemmX(const u16* __restrict__ A,
                                                   const u16* __restrict__ Bt,
                                                   void* C, int M, int N, int K){
  __shared__ u16 L[65536];                   // slot s: A @ s*16384, B @ +8192 (u16)
  const int t = threadIdx.x;
  const int w = t >> 6, lane = t & 63, l15 = lane & 15, g = lane >> 4;
  const int wr = w >> 2, wc = w & 3;
  const int nbm = M >> 8;
  int id = blockIdx.x;
  {
    const int cpx = gridDim.x >> 3;
    id = (id & 7) * cpx + (id >> 3);
  }
  const int bm = id % nbm, bn = id / nbm;
  const int NT = K >> 5;

  const int Rp0 = t >> 3;
  const int u0  = (t & 7) ^ (Rp0 & 7);
  const int R0  = (Rp0 << 1) | (u0 >> 2);
  const int kc0 = (u0 & 3) << 3;
  const u16* pA = A  + ((long)bm * 256 + R0) * (long)K + kc0;
  const u16* pB = Bt + ((long)bn * 256 + R0) * (long)K + kc0;
  const int w0 = (t & ~63) * 8;

  auto stage = [&](int s){
    u16* d = L + s * 16384;
    GLOAD_LDS16(pA, d + w0);
    GLOAD_LDS16(pB, d + 8192 + w0);
    pA += 32; pB += 32;
  };

  stage(0); stage(1); stage(2);
  asm volatile("s_waitcnt vmcnt(4)" ::: "memory");
  __builtin_amdgcn_s_barrier();

  f32x4 acc[4][4] = {};
  for (int tt = 0; tt < NT; ++tt){
    const int slot = tt & 3;
    const u16* sA = L + slot * 16384;
    const u16* sB = sA + 8192;
    bf16x8 af[4], bfr[4];
    #pragma unroll
    for (int mi = 0; mi < 4; ++mi)
      af[mi] = lds_frag(sA, wr * 64 + mi * 16 + l15, g);
    #pragma unroll
    for (int ni = 0; ni < 4; ++ni)
      bfr[ni] = lds_frag(sB, wc * 64 + ni * 16 + l15, g);
    if (tt + 3 < NT) stage((tt + 3) & 3);
    asm volatile("s_waitcnt lgkmcnt(0)" ::: "memory");
    if (tt + 3 < NT)      asm volatile("s_waitcnt vmcnt(4)" ::: "memory");
    else if (tt + 2 < NT) asm volatile("s_waitcnt vmcnt(2)" ::: "memory");
    else if (tt + 1 < NT) asm volatile("s_waitcnt vmcnt(0)" ::: "memory");
    __builtin_amdgcn_s_barrier();
    __builtin_amdgcn_s_setprio(1);
    #pragma unroll
    for (int mi = 0; mi < 4; ++mi)
      #pragma unroll
      for (int ni = 0; ni < 4; ++ni)
        acc[mi][ni] = mfma16(af[mi], bfr[ni], acc[mi][ni]);
    __builtin_amdgcn_s_setprio(0);
  }
  const int row0 = bm * 256 + wr * 64, col0 = bn * 256 + wc * 64;
  #pragma unroll
  for (int mi = 0; mi < 4; ++mi){
    #pragma unroll
    for (int ni = 0; ni < 4; ++ni){
      #pragma unroll
      for (int r = 0; r < 4; ++r){
        const long ri = row0 + mi * 16 + g * 4 + r;
        const long ci = col0 + ni * 16 + l15;
        const float v = acc[mi][ni][r];
        if (OUT_BF16) ((u16*)C)[ri * N + ci] = f2bf(v);
        else          ((float*)C)[ri * N + ci] = v;
      }
    }
  }
}

// ------- GEMM 256x256 + fused SwiGLU epilogue (mlp_in, interleaved weights) ------
__global__ __launch_bounds__(1024, 4) void k_gemmXswi(const u16* __restrict__ A,
                                                      const u16* __restrict__ Bt,
                                                      u16* __restrict__ O,
                                                      int M, int K){
  __shared__ u16 L[65536];
  const int t = threadIdx.x;
  const int w = t >> 6, lane = t & 63, l15 = lane & 15, g = lane >> 4;
  const int wr = w >> 2, wc = w & 3;
  const int nbm = M >> 8;
  int id = blockIdx.x;
  {
    const int cpx = gridDim.x >> 3;
    id = (id & 7) * cpx + (id >> 3);
  }
  const int bm = id % nbm, bn = id / nbm;
  const int NT = K >> 5;

  const int Rp0 = t >> 3;
  const int u0  = (t & 7) ^ (Rp0 & 7);
  const int R0  = (Rp0 << 1) | (u0 >> 2);
  const int kc0 = (u0 & 3) << 3;
  const u16* pA = A  + ((long)bm * 256 + R0) * (long)K + kc0;
  const u16* pB = Bt + ((long)bn * 256 + R0) * (long)K + kc0;
  const int w0 = (t & ~63) * 8;

  auto stage = [&](int s){
    u16* d = L + s * 16384;
    GLOAD_LDS16(pA, d + w0);
    GLOAD_LDS16(pB, d + 8192 + w0);
    pA += 32; pB += 32;
  };

  stage(0); stage(1); stage(2);
  asm volatile("s_waitcnt vmcnt(4)" ::: "memory");
  __builtin_amdgcn_s_barrier();

  f32x4 acc[4][4] = {};
  for (int tt = 0; tt < NT; ++tt){
    const int slot = tt & 3;
    const u16* sA = L + slot * 16384;
    const u16* sB = sA + 8192;
    bf16x8 af[4], bfr[4];
    #pragma unroll
    for (int mi = 0; mi < 4; ++mi)
      af[mi] = lds_frag(sA, wr * 64 + mi * 16 + l15, g);
    #pragma unroll
    for (int ni = 0; ni < 4; ++ni)
      bfr[ni] = lds_frag(sB, wc * 64 + ni * 16 + l15, g);
    if (tt + 3 < NT) stage((tt + 3) & 3);
    asm volatile("s_waitcnt lgkmcnt(0)" ::: "memory");
    if (tt + 3 < NT)      asm volatile("s_waitcnt vmcnt(4)" ::: "memory");
    else if (tt + 2 < NT) asm volatile("s_waitcnt vmcnt(2)" ::: "memory");
    else if (tt + 1 < NT) asm volatile("s_waitcnt vmcnt(0)" ::: "memory");
    __builtin_amdgcn_s_barrier();
    __builtin_amdgcn_s_setprio(1);
    #pragma unroll
    for (int mi = 0; mi < 4; ++mi)
      #pragma unroll
      for (int ni = 0; ni < 4; ++ni)
        acc[mi][ni] = mfma16(af[mi], bfr[ni], acc[mi][ni]);
    __builtin_amdgcn_s_setprio(0);
  }
  // ---- fused SwiGLU epilogue ----
  __syncthreads();
  float* U = (float*)L;
  if (wc >= 2){
    const int base = ((wr << 1) | (wc - 2)) * 4096;
    #pragma unroll
    for (int mi = 0; mi < 4; ++mi)
      #pragma unroll
      for (int ni = 0; ni < 4; ++ni)
        #pragma unroll
        for (int r = 0; r < 4; ++r)
          U[base + (mi * 16 + g * 4 + r) * 64 + ni * 16 + l15] = acc[mi][ni][r];
  }
  __syncthreads();
  if (wc < 2){
    const int base = ((wr << 1) | wc) * 4096;
    #pragma unroll
    for (int mi = 0; mi < 4; ++mi){
      #pragma unroll
      for (int ni = 0; ni < 4; ++ni){
        #pragma unroll
        for (int r = 0; r < 4; ++r){
          const float gv = acc[mi][ni][r];
          const float uv = U[base + (mi * 16 + g * 4 + r) * 64 + ni * 16 + l15];
          const float ov = gv / (1.f + __expf(-gv)) * uv;
          const long ri = bm * 256 + wr * 64 + mi * 16 + g * 4 + r;
          const int ci = bn * 128 + wc * 64 + ni * 16 + l15;
          O[ri * PDIM + ci] = f2bf(ov);
        }
      }
    }
  }
}

// -------------------- RoPE in-place on bf16 qkv --------------------
__global__ void k_rope(u16* __restrict__ qkv){
  const int idx = blockIdx.x * 256 + threadIdx.x;   // S * 20 * 64
  const int i = idx & 63;
  const int head = (idx >> 6) % 20;
  const int s = idx / (64 * 20);
  const long base = (long)s * NQKV + (head < NHQ ? head * HDIM : DMODEL + (head - NHQ) * HDIM);
  u32* p = (u32*)(qkv + base + 2 * i);
  const u32 v = *p;
  const float x0 = bf2f((u16)(v & 0xffffu)), x1 = bf2f((u16)(v >> 16));
  const float ang = (float)s * exp2f(-0.29580575889569023f * (float)i);
  float sn, cs;
  sincosf(ang, &sn, &cs);
  const float y0 = x0 * cs - x1 * sn;
  const float y1 = x0 * sn + x1 * cs;
  *p = (u32)f2bf(y0) | ((u32)f2bf(y1) << 16);
}

// ------------- Flash attention (R13/R15-proven): XCD-pinned kh + LPT ordering ----
__global__ __launch_bounds__(256) void k_attn(const u16* __restrict__ qkv,
                                              const u16* __restrict__ vT,
                                              u16* __restrict__ o){
  const int id = blockIdx.x;
  const int xcd = id & 7, j = id >> 3;
  const int kh = xcd >> 1;
  const int h  = (kh << 2) + ((xcd & 1) << 1) + (j & 1);
  const int qb = 31 - (j >> 1);
  const int t = threadIdx.x, w = t >> 6, lane = t & 63, l15 = lane & 15, g = lane >> 4;
  __shared__ u16 Ks[2][8192];
  __shared__ u16 Vs[2][8192];
  __shared__ u16 Ps[4][16 * 72];
  const int q0 = qb * 64 + w * 16;
  bf16x8 aq[4];
  #pragma unroll
  for (int d0 = 0; d0 < 4; ++d0)
    aq[d0] = ld8(qkv + (long)(q0 + l15) * NQKV + h * HDIM + d0 * 32 + g * 8);
  f32x4 acc_o[8] = {};
  float mst[4], lst[4];
  #pragma unroll
  for (int r = 0; r < 4; ++r){ mst[r] = -1e30f; lst[r] = 0.f; }
  const float scale = 0.08838834764831843f;

  auto stageK = [&](int kt, int b){
    #pragma unroll
    for (int p = 0; p < 4; ++p){
      const int q = p * 256 + t;
      const int r = q >> 4, u = q & 15;
      const u16* gp = qkv + (long)(kt * 64 + r) * NQKV + DMODEL + kh * HDIM + ((u ^ (r & 15)) << 3);
      GLOAD_LDS16(gp, Ks[b] + (p * 256 + (t & ~63)) * 8);
    }
  };
  auto stageV = [&](int kt, int b){
    #pragma unroll
    for (int p = 0; p < 4; ++p){
      const int q = p * 256 + t;
      const int r = q >> 3, u = q & 7;
      const u16* gp = vT + ((long)kh * HDIM + r) * S_LEN + kt * 64 + ((u ^ (r & 7)) << 3);
      GLOAD_LDS16(gp, Vs[b] + (p * 256 + (t & ~63)) * 8);
    }
  };

  const int nkt = qb + 1;
  stageK(0, 0); stageV(0, 0);
  for (int kt = 0; kt < nkt; ++kt){
    const int kv0 = kt << 6;
    __builtin_amdgcn_s_barrier();            // (a) prev reads drained -> DMA may overwrite
    if (kt + 1 < nkt){
      stageK(kt + 1, (kt + 1) & 1);
      stageV(kt + 1, (kt + 1) & 1);
      asm volatile("s_waitcnt vmcnt(8)" ::: "memory");
    } else {
      asm volatile("s_waitcnt vmcnt(0)" ::: "memory");
    }
    __builtin_amdgcn_s_barrier();            // (b) tile kt globally visible
    const u16* K_ = Ks[kt & 1];
    const u16* V_ = Vs[kt & 1];
    // ---- S = Q K^T ----
    f32x4 sacc[4] = {};
    #pragma unroll
    for (int d0 = 0; d0 < 4; ++d0){
      #pragma unroll
      for (int j2 = 0; j2 < 4; ++j2){
        const bf16x8 bk = ld8(K_ + (j2 * 16 + l15) * 128 + ((((d0 << 2) | g) ^ l15) << 3));
        sacc[j2] = mfma16(aq[d0], bk, sacc[j2]);
      }
    }
    // ---- mask + online softmax (rows in 16-lane groups) ----
    float p[4][4], scl[4];
    #pragma unroll
    for (int r = 0; r < 4; ++r){
      const int qrow = q0 + g * 4 + r;
      float mx = -1e30f;
      #pragma unroll
      for (int j2 = 0; j2 < 4; ++j2){
        float sv = sacc[j2][r] * scale;
        sv = (kv0 + j2 * 16 + l15 <= qrow) ? sv : -1e30f;
        p[j2][r] = sv;
        mx = fmaxf(mx, sv);
      }
      #pragma unroll
      for (int off = 1; off < 16; off <<= 1) mx = fmaxf(mx, __shfl_xor(mx, off, 64));
      const float mnew = fmaxf(mst[r], mx);
      scl[r] = __expf(mst[r] - mnew);
      float rs = 0.f;
      #pragma unroll
      for (int j2 = 0; j2 < 4; ++j2){ p[j2][r] = __expf(p[j2][r] - mnew); rs += p[j2][r]; }
      #pragma unroll
      for (int off = 1; off < 16; off <<= 1) rs += __shfl_xor(rs, off, 64);
      lst[r] = lst[r] * scl[r] + rs;
      mst[r] = mnew;
    }
    #pragma unroll
    for (int n = 0; n < 8; ++n)
      #pragma unroll
      for (int r = 0; r < 4; ++r)
        acc_o[n][r] *= scl[r];
    // ---- P -> LDS (per-wave), then PV ----
    #pragma unroll
    for (int j2 = 0; j2 < 4; ++j2)
      #pragma unroll
      for (int r = 0; r < 4; ++r)
        Ps[w][(g * 4 + r) * 72 + j2 * 16 + l15] = f2bf(p[j2][r]);
    #pragma unroll
    for (int kk = 0; kk < 2; ++kk){
      const bf16x8 pa = ld8(Ps[w] + l15 * 72 + kk * 32 + g * 8);
      #pragma unroll
      for (int n = 0; n < 8; ++n){
        const int row = n * 16 + l15;
        const bf16x8 bv = ld8(V_ + row * 64 + ((((kk << 2) | g) ^ (l15 & 7)) << 3));
        acc_o[n] = mfma16(pa, bv, acc_o[n]);
      }
    }
    asm volatile("s_waitcnt lgkmcnt(0)" ::: "memory");   // drain my LDS reads (WAR)
  }
  #pragma unroll
  for (int n = 0; n < 8; ++n){
    #pragma unroll
    for (int r = 0; r < 4; ++r){
      const float ov = acc_o[n][r] / lst[r];
      o[(long)(q0 + g * 4 + r) * DMODEL + h * HDIM + n * 16 + l15] = f2bf(ov);
    }
  }
}

// -------------------- launch --------------------
extern "C" void kernel_launch(void* const* d_in, const int* in_sizes, int n_in,
                              void* d_out, int out_size, void* d_ws, size_t ws_size,
                              hipStream_t stream){
  const int*   tokens       = (const int*)d_in[0];
  const float* embed        = (const float*)d_in[1];
  const float* attn_norm_w  = (const float*)d_in[2];
  const float* qkv_w        = (const float*)d_in[3];
  const float* attn_out_w   = (const float*)d_in[4];
  const float* mlp_norm_w   = (const float*)d_in[5];
  const float* mlp_in_w     = (const float*)d_in[6];
  const float* mlp_out_w    = (const float*)d_in[7];
  const float* final_norm_w = (const float*)d_in[8];
  const float* lm_head_w    = (const float*)d_in[9];

  char* ws = (char*)d_ws;
  float* xf  = (float*)(ws);                    // 16.78 MB residual (fp32)
  u16* hbf   = (u16*)(ws + 16777216);           //  8.39 MB normed activations
  u16* qkvb  = (u16*)(ws + 25165824);           // 12.58 MB qkv
  u16* obf   = (u16*)(ws + 37748736);           //  8.39 MB attn out
  u16* gub   = (u16*)(ws + 46137344);           // 67.11 MB (fp32 partials region)
  u16* hb2   = (u16*)(ws + 113246208);          // 33.55 MB silu(g)*u
  u16* wbuf  = (u16*)(ws + 146800640);          // 131.07 MB transposed bf16 weights
  u16* vTb   = (u16*)(ws + 277872640);          //  2.10 MB transposed V
  float* pp  = (float*)gub;                     // 33.55 MB: 2 x [2048x2048] fp32 partials

  k_embed<<<S_LEN, 256, 0, stream>>>(tokens, embed, xf);
  k_rmsnorm<<<S_LEN, 256, 0, stream>>>(xf, attn_norm_w, hbf);
  for (int l = 0; l < 2; ++l){
    k_convT<<<dim3(NQKV/64, DMODEL/64), 256, 0, stream>>>(
        qkv_w + (long)l * DMODEL * NQKV, wbuf, NQKV, DMODEL);
    k_gemm<1,0><<<(S_LEN/128) * (NQKV/128), 256, 0, stream>>>(
        hbf, wbuf, qkvb, nullptr, S_LEN, NQKV, DMODEL, NQKV/128, 4);
    k_rope<<<(S_LEN * 20 * 64) / 256, 256, 0, stream>>>(qkvb);
    k_transV<<<dim3(S_LEN/64, 2, 4), 256, 0, stream>>>(qkvb, vTb);
    k_attn<<<512, 256, 0, stream>>>(qkvb, vTb, obf);
    // attn_out: split-K=2 (2 blocks/CU) + fused residual-add + mlp RMSNorm
    k_convT<<<dim3(DMODEL/64, DMODEL/64), 256, 0, stream>>>(
        attn_out_w + (long)l * DMODEL * DMODEL, wbuf, DMODEL, DMODEL);
    k_gemmsk<<<dim3((S_LEN/128) * (DMODEL/128), 2), 256, 0, stream>>>(
        obf, wbuf, pp, S_LEN, DMODEL, DMODEL, DMODEL/128, 4);
    k_red2rms<<<S_LEN, 256, 0, stream>>>(
        xf, pp, pp + (long)S_LEN * DMODEL, mlp_norm_w + (long)l * DMODEL, hbf);
    // mlp_in + fused SwiGLU
    k_convTmi<<<dim3((2*PDIM)/64, DMODEL/64), 256, 0, stream>>>(
        mlp_in_w + (long)l * DMODEL * 2 * PDIM, wbuf, 2*PDIM, DMODEL);
    k_gemmXswi<<<(S_LEN/256) * ((2*PDIM)/256), 1024, 0, stream>>>(
        hbf, wbuf, hb2, S_LEN, DMODEL);
    // mlp_out: split-K=2 + fused residual-add + next-layer/final RMSNorm
    k_convT<<<dim3(DMODEL/64, PDIM/64), 256, 0, stream>>>(
        mlp_out_w + (long)l * PDIM * DMODEL, wbuf, DMODEL, PDIM);
    k_gemmsk<<<dim3((S_LEN/128) * (DMODEL/128), 2), 256, 0, stream>>>(
        hb2, wbuf, pp, S_LEN, DMODEL, PDIM, DMODEL/128, 2);
    k_red2rms<<<S_LEN, 256, 0, stream>>>(
        xf, pp, pp + (long)S_LEN * DMODEL,
        (l == 0) ? (attn_norm_w + DMODEL) : final_norm_w, hbf);
  }
  k_convT<<<dim3(VOCAB/64, DMODEL/64), 256, 0, stream>>>(lm_head_w, wbuf, VOCAB, DMODEL);
  k_gemmX<0><<<(S_LEN/256) * (VOCAB/256), 1024, 0, stream>>>(
      hbf, wbuf, (float*)d_out, S_LEN, VOCAB, DMODEL);
}